// Round 1
// baseline (300.067 us; speedup 1.0000x reference)
//
#include <hip/hip_runtime.h>
#include <hip/hip_bf16.h>

typedef __bf16 bf16x8 __attribute__((ext_vector_type(8)));
typedef __bf16 bf16x4 __attribute__((ext_vector_type(4)));
typedef float  f32x4  __attribute__((ext_vector_type(4)));

#define S_LEN 2048
#define DH    64
#define QB    64
#define KVB   64

// Swizzled LDS element offset for a [rows][64] bf16 tile (128B row stride).
// 16B chunk index within the row is XORed with (row&7): spreads the
// column-slice b128 reads across all 8 chunk slots -> conflict-free.
__device__ __forceinline__ int swz(int row, int col) {
    return (row << 6) + ((((col >> 3) ^ row) & 7) << 3) + (col & 7);
}

__launch_bounds__(256, 2)
__global__ void attn_fwd(const float* __restrict__ Kg,
                         const float* __restrict__ Qg,
                         const float* __restrict__ Vg,
                         float* __restrict__ Og) {
    __shared__ __bf16 Klds[64 * 64];      // [kv][d]   swizzled
    __shared__ __bf16 Vlds[64 * 64];      // [d][kv]   transposed, swizzled
    __shared__ __bf16 Plds[4][16 * 64];   // per-wave  [q][kv] swizzled

    const int qb  = blockIdx.x;
    const int bh  = blockIdx.y;
    const int tid = threadIdx.x;
    const int w   = tid >> 6;
    const int l   = tid & 63;
    const int lo  = l & 15;
    const int hi  = l >> 4;

    const int    q0   = qb * QB;
    const size_t base = (size_t)bh * S_LEN * DH;
    const float* Kb = Kg + base;
    const float* Qb = Qg + base;
    const float* Vb = Vg + base;
    float*       Ob = Og + base;

    // ---- Q fragments in registers, softmax scale (1/8, exact) folded in ----
    bf16x8 aq[2];
    {
        const int qrow = q0 + w * 16 + lo;
        for (int dc = 0; dc < 2; ++dc) {
            const float* p = Qb + (size_t)qrow * DH + dc * 32 + hi * 8;
            f32x4 v0 = *(const f32x4*)p;
            f32x4 v1 = *(const f32x4*)(p + 4);
            for (int j = 0; j < 4; ++j) {
                aq[dc][j]     = (__bf16)(v0[j] * 0.125f);
                aq[dc][j + 4] = (__bf16)(v1[j] * 0.125f);
            }
        }
    }

    f32x4 oacc[4];
    for (int n = 0; n < 4; ++n) oacc[n] = (f32x4){0.f, 0.f, 0.f, 0.f};
    float mrow[4], lrow[4];
    for (int r = 0; r < 4; ++r) { mrow[r] = -1e30f; lrow[r] = 0.f; }

    for (int t = 0; t <= qb; ++t) {
        const int kv0 = t * KVB;

        // ---- stage K (row-major) and V (transposed) into LDS as bf16 ----
        {
            const int rr = tid >> 4;         // 0..15
            const int c4 = (tid & 15) * 4;   // 0,4,..,60
            for (int i = 0; i < 4; ++i) {
                const int row = i * 16 + rr; // 0..63
                f32x4 k4 = *(const f32x4*)(Kb + (size_t)(kv0 + row) * DH + c4);
                bf16x4 kb;
                for (int j = 0; j < 4; ++j) kb[j] = (__bf16)k4[j];
                *(bf16x4*)&Klds[swz(row, c4)] = kb;
                f32x4 v4 = *(const f32x4*)(Vb + (size_t)(kv0 + row) * DH + c4);
                for (int j = 0; j < 4; ++j)
                    Vlds[swz(c4 + j, row)] = (__bf16)v4[j];
            }
        }
        __syncthreads();

        // ---- S = (Q*scale) K^T : A=Q(m=q), B=K(n=kv), k-slot d consistent ----
        f32x4 sc[4];
        for (int c = 0; c < 4; ++c) {
            f32x4 acc = (f32x4){0.f, 0.f, 0.f, 0.f};
            for (int dc = 0; dc < 2; ++dc) {
                bf16x8 bk = *(const bf16x8*)&Klds[swz(c * 16 + lo, dc * 32 + hi * 8)];
                acc = __builtin_amdgcn_mfma_f32_16x16x32_bf16(aq[dc], bk, acc, 0, 0, 0);
            }
            sc[c] = acc;
        }

        // ---- causal mask (only the diagonal tile; kv0==q0 there) ----
        if (t == qb) {
            const int qloc = w * 16 + hi * 4;           // + r
            for (int c = 0; c < 4; ++c)
                for (int r = 0; r < 4; ++r)
                    if (c * 16 + lo > qloc + r) sc[c][r] = -1e30f;
        }

        // ---- online softmax (rows replicated over the 16 lanes of same hi) ----
        float pm[4];
        for (int r = 0; r < 4; ++r)
            pm[r] = fmaxf(fmaxf(sc[0][r], sc[1][r]), fmaxf(sc[2][r], sc[3][r]));
        for (int m = 1; m < 16; m <<= 1)
            for (int r = 0; r < 4; ++r)
                pm[r] = fmaxf(pm[r], __shfl_xor(pm[r], m, 64));

        float fr[4], mn[4];
        for (int r = 0; r < 4; ++r) {
            mn[r]   = fmaxf(mrow[r], pm[r]);
            fr[r]   = __expf(mrow[r] - mn[r]);
            mrow[r] = mn[r];
        }
        float rs[4] = {0.f, 0.f, 0.f, 0.f};
        for (int c = 0; c < 4; ++c)
            for (int r = 0; r < 4; ++r) {
                float p = __expf(sc[c][r] - mn[r]);
                sc[c][r] = p;
                rs[r] += p;
            }
        for (int m = 1; m < 16; m <<= 1)
            for (int r = 0; r < 4; ++r)
                rs[r] += __shfl_xor(rs[r], m, 64);
        for (int r = 0; r < 4; ++r) lrow[r] = lrow[r] * fr[r] + rs[r];
        for (int n = 0; n < 4; ++n)
            for (int r = 0; r < 4; ++r) oacc[n][r] *= fr[r];

        // ---- P -> per-wave LDS (layout fix C/D -> A-fragment) ----
        __bf16* pl = &Plds[w][0];
        for (int c = 0; c < 4; ++c)
            for (int r = 0; r < 4; ++r)
                pl[swz(hi * 4 + r, c * 16 + lo)] = (__bf16)sc[c][r];
        // wave-local DS ops complete in order: no barrier needed before reads

        // ---- O += P V : A=P(m=q), B=V_T(n=d), k-slot kv consistent ----
        for (int kc = 0; kc < 2; ++kc) {
            bf16x8 pf = *(const bf16x8*)&pl[swz(lo, kc * 32 + hi * 8)];
            for (int n = 0; n < 4; ++n) {
                bf16x8 vf = *(const bf16x8*)&Vlds[swz(n * 16 + lo, kc * 32 + hi * 8)];
                oacc[n] = __builtin_amdgcn_mfma_f32_16x16x32_bf16(pf, vf, oacc[n], 0, 0, 0);
            }
        }
        __syncthreads();   // protect K/V LDS before next tile's staging
    }

    // ---- epilogue: O / l ----
    for (int n = 0; n < 4; ++n)
        for (int r = 0; r < 4; ++r) {
            const int q = q0 + w * 16 + hi * 4 + r;
            Ob[(size_t)q * DH + n * 16 + lo] = oacc[n][r] / lrow[r];
        }
}

extern "C" void kernel_launch(void* const* d_in, const int* in_sizes, int n_in,
                              void* d_out, int out_size, void* d_ws, size_t ws_size,
                              hipStream_t stream) {
    const float* keys    = (const float*)d_in[0];
    const float* queries = (const float*)d_in[1];
    const float* values  = (const float*)d_in[2];
    float* out = (float*)d_out;

    const int BH = in_sizes[0] / (S_LEN * DH);   // B*H = 64
    dim3 grid(S_LEN / QB, BH);
    dim3 block(256);
    attn_fwd<<<grid, block, 0, stream>>>(keys, queries, values, out);
}

// Round 2
// 182.310 us; speedup vs baseline: 1.6459x; 1.6459x over previous
//
#include <hip/hip_runtime.h>
#include <hip/hip_bf16.h>

typedef __bf16 bf16x8 __attribute__((ext_vector_type(8)));
typedef __bf16 bf16x4 __attribute__((ext_vector_type(4)));
typedef float  f32x4  __attribute__((ext_vector_type(4)));

#define S_LEN 2048
#define DH    64
#define QB    64
#define KVB   64

// Swizzled LDS element offset for a [rows][64] bf16 tile (128B row stride).
// 16B chunk index within the row is XORed with (row&7): column-slice b128
// reads/writes spread across all 8 chunk slots -> conflict-free.
__device__ __forceinline__ int swz(int row, int col) {
    return (row << 6) + ((((col >> 3) ^ row) & 7) << 3) + (col & 7);
}

__launch_bounds__(256, 4)
__global__ void attn_fwd(const float* __restrict__ Kg,
                         const float* __restrict__ Qg,
                         const float* __restrict__ Vg,
                         float* __restrict__ Og) {
    __shared__ __bf16 Klds[64 * 64];   // [kv][d]                 swizzled
    __shared__ __bf16 Vlds[64 * 64];   // [d][slot], kv=pi(slot)  swizzled

    const int qb  = blockIdx.x;
    const int bh  = blockIdx.y;
    const int tid = threadIdx.x;
    const int w   = tid >> 6;
    const int l   = tid & 63;
    const int lo  = l & 15;
    const int hi  = l >> 4;

    const int    q0   = qb * QB;
    const size_t base = (size_t)bh * S_LEN * DH;
    const float* Kb = Kg + base;
    const float* Qb = Qg + base;
    const float* Vb = Vg + base;
    float*       Ob = Og + base;

    // ---- Q fragments (B-operand of swapped QK^T): lane holds Q[q=lo][d-slots]
    // softmax scale (1/8, exact) folded into the bf16 conversion
    bf16x8 bq[2];
    {
        const int qrow = q0 + w * 16 + lo;
        #pragma unroll
        for (int dc = 0; dc < 2; ++dc) {
            const float* p = Qb + (size_t)qrow * DH + dc * 32 + hi * 8;
            f32x4 v0 = *(const f32x4*)p;
            f32x4 v1 = *(const f32x4*)(p + 4);
            #pragma unroll
            for (int j = 0; j < 4; ++j) {
                bq[dc][j]     = (__bf16)(v0[j] * 0.125f);
                bq[dc][j + 4] = (__bf16)(v1[j] * 0.125f);
            }
        }
    }

    // O^T accumulators: oacc[n][r] = O^T[d = n*16 + hi*4 + r][q = lo]
    f32x4 oacc[4];
    #pragma unroll
    for (int n = 0; n < 4; ++n) oacc[n] = (f32x4){0.f, 0.f, 0.f, 0.f};
    float mrow = -1e30f, lrow = 0.f;

    // staging index precompute
    const int krr = tid >> 4;          // 0..15  (K-staging row within 16-group)
    const int kc4 = (tid & 15) * 4;    // 0..60  (K-staging col)

    for (int t = 0; t <= qb; ++t) {
        const int kv0 = t * KVB;

        // ---- stage K rows (vectorized) ----
        {
            const float* kp = Kb + (size_t)kv0 * DH + kc4;
            #pragma unroll
            for (int i = 0; i < 4; ++i) {
                const int row = i * 16 + krr;
                f32x4 k4 = *(const f32x4*)(kp + (size_t)row * DH);
                bf16x4 kb;
                #pragma unroll
                for (int j = 0; j < 4; ++j) kb[j] = (__bf16)k4[j];
                *(bf16x4*)&Klds[swz(row, kc4)] = kb;
            }
        }
        // ---- stage V^T with pi-permuted kv axis (vectorized b128 writes) ----
        // Vlds[d][s] = V[kv0 + pi(s)][d],  pi(s) = (kc*2+(j>>2))*16 + hs*4 + (j&3)
        // where kc=s>>5, hs=(s>>3)&3, j=s&7.  Wave w owns slots w*16..w*16+15,
        // lane l supplies d = l (coalesced 256B global row reads).
        {
            const float* vp = Vb + (size_t)kv0 * DH + l;
            float vv[16];
            #pragma unroll
            for (int i = 0; i < 16; ++i) {
                const int s  = w * 16 + i;
                const int kc = s >> 5, hs = (s >> 3) & 3, j = s & 7;
                const int kv = (kc * 2 + (j >> 2)) * 16 + hs * 4 + (j & 3);
                vv[i] = vp[(size_t)kv * DH];
            }
            bf16x8 v0, v1;
            #pragma unroll
            for (int i = 0; i < 8; ++i) { v0[i] = (__bf16)vv[i]; v1[i] = (__bf16)vv[8 + i]; }
            *(bf16x8*)&Vlds[swz(l, w * 16)]     = v0;
            *(bf16x8*)&Vlds[swz(l, w * 16 + 8)] = v1;
        }
        __syncthreads();

        // ---- S^T = K (Q*scale)^T : sc[c][r] = S^T[kv=c*16+hi*4+r][q=lo] ----
        const bool diag = (t == qb);
        const int  cmax = diag ? (w + 1) : 4;
        f32x4 sc[4];
        #pragma unroll
        for (int c = 0; c < 4; ++c) {
            if (c < cmax) {
                f32x4 acc = (f32x4){0.f, 0.f, 0.f, 0.f};
                #pragma unroll
                for (int dc = 0; dc < 2; ++dc) {
                    bf16x8 ak = *(const bf16x8*)&Klds[swz(c * 16 + lo, dc * 32 + hi * 8)];
                    acc = __builtin_amdgcn_mfma_f32_16x16x32_bf16(ak, bq[dc], acc, 0, 0, 0);
                }
                sc[c] = acc;
            } else {
                sc[c] = (f32x4){-1e30f, -1e30f, -1e30f, -1e30f};
            }
        }
        // causal mask: only the c==w sub-tile of the diagonal tile needs it
        if (diag) {
            #pragma unroll
            for (int r = 0; r < 4; ++r)
                if (hi * 4 + r > lo) sc[w][r] = -1e30f;
        }

        // ---- online softmax: q-column is lane-local (16 vals) + 4-group reduce
        float pm = -1e30f;
        #pragma unroll
        for (int c = 0; c < 4; ++c)
            #pragma unroll
            for (int r = 0; r < 4; ++r) pm = fmaxf(pm, sc[c][r]);
        pm = fmaxf(pm, __shfl_xor(pm, 16, 64));
        pm = fmaxf(pm, __shfl_xor(pm, 32, 64));

        const float mn = fmaxf(mrow, pm);
        const float fr = __expf(mrow - mn);
        mrow = mn;
        float rs = 0.f;
        #pragma unroll
        for (int c = 0; c < 4; ++c)
            #pragma unroll
            for (int r = 0; r < 4; ++r) {
                float p = __expf(sc[c][r] - mn);
                sc[c][r] = p;
                rs += p;
            }
        rs += __shfl_xor(rs, 16, 64);
        rs += __shfl_xor(rs, 32, 64);
        lrow = lrow * fr + rs;
        #pragma unroll
        for (int n = 0; n < 4; ++n) oacc[n] *= fr;

        // ---- pack P^T into PV B-fragments, k-slot pi-consistent with Vlds ----
        bf16x8 pb[2];
        #pragma unroll
        for (int kc = 0; kc < 2; ++kc)
            #pragma unroll
            for (int j = 0; j < 8; ++j)
                pb[kc][j] = (__bf16)sc[kc * 2 + (j >> 2)][j & 3];

        // ---- O^T += V^T P^T ----
        #pragma unroll
        for (int n = 0; n < 4; ++n) {
            #pragma unroll
            for (int kc = 0; kc < 2; ++kc) {
                bf16x8 av = *(const bf16x8*)&Vlds[swz(n * 16 + lo, kc * 32 + hi * 8)];
                oacc[n] = __builtin_amdgcn_mfma_f32_16x16x32_bf16(av, pb[kc], oacc[n], 0, 0, 0);
            }
        }
        __syncthreads();   // protect K/V LDS before next tile's staging
    }

    // ---- epilogue: lane holds 16 d-values of one q row -> 4x f32x4 stores ----
    const float linv = 1.0f / lrow;
    const int   q    = q0 + w * 16 + lo;
    #pragma unroll
    for (int n = 0; n < 4; ++n) {
        f32x4 o;
        #pragma unroll
        for (int r = 0; r < 4; ++r) o[r] = oacc[n][r] * linv;
        *(f32x4*)(Ob + (size_t)q * DH + n * 16 + hi * 4) = o;
    }
}

extern "C" void kernel_launch(void* const* d_in, const int* in_sizes, int n_in,
                              void* d_out, int out_size, void* d_ws, size_t ws_size,
                              hipStream_t stream) {
    const float* keys    = (const float*)d_in[0];
    const float* queries = (const float*)d_in[1];
    const float* values  = (const float*)d_in[2];
    float* out = (float*)d_out;

    const int BH = in_sizes[0] / (S_LEN * DH);   // B*H = 64
    dim3 grid(S_LEN / QB, BH);
    dim3 block(256);
    attn_fwd<<<grid, block, 0, stream>>>(keys, queries, values, out);
}